// Round 2
// baseline (2799.600 us; speedup 1.0000x reference)
//
#include <hip/hip_runtime.h>
#include <hip/hip_bf16.h>

#define NB 8
#define SS 2048
#define TT 2048
#define DD 1024
#define NEG_BIG -1000000000.0f

// ---------------- K1: scores[s,t] = mask(s) ? -1e9 : sum_d state[b,s,d]*x[b,t,d]
// GEMM-NT: A [M=S x K=D] row-major f32, B [N=T x K=D] row-major f32, C [S x T] f32
__global__ __launch_bounds__(256) void k1_scores(
    const float* __restrict__ state,
    const float* __restrict__ x,
    const int* __restrict__ src,
    float* __restrict__ scores, int b0)
{
    __shared__ float As[32][68]; // [k][m]
    __shared__ float Bs[32][68]; // [k][n]
    const int g = blockIdx.z, b = b0 + g;
    const int m0 = blockIdx.y * 64; // s
    const int n0 = blockIdx.x * 64; // t
    const int tid = threadIdx.x;
    const float* Ab = state + (size_t)b * SS * DD;
    const float* Bb = x     + (size_t)b * TT * DD;
    const int lr = tid >> 2;          // 0..63 row (m or n)
    const int lc = (tid & 3) * 8;     // k chunk
    const int ty = tid >> 4, tx = tid & 15;
    float acc[4][4] = {};
    for (int k0 = 0; k0 < DD; k0 += 32) {
        const float* ap = Ab + (size_t)(m0 + lr) * DD + k0 + lc;
        const float* bp = Bb + (size_t)(n0 + lr) * DD + k0 + lc;
        float4 a0 = *reinterpret_cast<const float4*>(ap);
        float4 a1 = *reinterpret_cast<const float4*>(ap + 4);
        float4 b0v = *reinterpret_cast<const float4*>(bp);
        float4 b1v = *reinterpret_cast<const float4*>(bp + 4);
        __syncthreads();
        As[lc + 0][lr] = a0.x; As[lc + 1][lr] = a0.y;
        As[lc + 2][lr] = a0.z; As[lc + 3][lr] = a0.w;
        As[lc + 4][lr] = a1.x; As[lc + 5][lr] = a1.y;
        As[lc + 6][lr] = a1.z; As[lc + 7][lr] = a1.w;
        Bs[lc + 0][lr] = b0v.x; Bs[lc + 1][lr] = b0v.y;
        Bs[lc + 2][lr] = b0v.z; Bs[lc + 3][lr] = b0v.w;
        Bs[lc + 4][lr] = b1v.x; Bs[lc + 5][lr] = b1v.y;
        Bs[lc + 6][lr] = b1v.z; Bs[lc + 7][lr] = b1v.w;
        __syncthreads();
        #pragma unroll
        for (int kk = 0; kk < 32; ++kk) {
            float4 a4 = *reinterpret_cast<const float4*>(&As[kk][ty * 4]);
            float4 b4 = *reinterpret_cast<const float4*>(&Bs[kk][tx * 4]);
            float ar[4] = {a4.x, a4.y, a4.z, a4.w};
            float br[4] = {b4.x, b4.y, b4.z, b4.w};
            #pragma unroll
            for (int i = 0; i < 4; ++i)
                #pragma unroll
                for (int j = 0; j < 4; ++j)
                    acc[i][j] = fmaf(ar[i], br[j], acc[i][j]);
        }
    }
    float* Cg = scores + (size_t)g * SS * TT;
    #pragma unroll
    for (int i = 0; i < 4; ++i) {
        int s = m0 + ty * 4 + i;
        bool msk = (src[b * SS + s] == 0);
        #pragma unroll
        for (int j = 0; j < 4; ++j) {
            int t = n0 + tx * 4 + j;
            Cg[(size_t)s * TT + t] = msk ? NEG_BIG : acc[i][j];
        }
    }
}

// ---------------- K2: softmax over s (rows) per column t, in place.
__global__ __launch_bounds__(256) void k2_softmax_s(float* __restrict__ p)
{
    const int g = blockIdx.y;
    const int tc = threadIdx.x & 63;
    const int t = blockIdx.x * 64 + tc;
    const int sl = threadIdx.x >> 6; // 0..3
    float* base = p + (size_t)g * SS * TT + t;
    float m = -INFINITY, l = 0.f;
    for (int s = sl; s < SS; s += 4) {
        float v = base[(size_t)s * TT];
        if (v > m) { l = l * __expf(m - v) + 1.f; m = v; }
        else       { l += __expf(v - m); }
    }
    __shared__ float sm[4][64], sv[4][64];
    sm[sl][tc] = m; sv[sl][tc] = l;
    __syncthreads();
    float M = sm[0][tc];
    #pragma unroll
    for (int i = 1; i < 4; ++i) M = fmaxf(M, sm[i][tc]);
    float L = 0.f;
    #pragma unroll
    for (int i = 0; i < 4; ++i) L += sv[i][tc] * __expf(sm[i][tc] - M);
    float inv = 1.f / L;
    for (int s = sl; s < SS; s += 4) {
        size_t off = (size_t)s * TT;
        base[off] = __expf(base[off] - M) * inv;
    }
}

// ---------------- K3/K5: GEMM-TN: C[m,n] = sum_k A[k,m] * B[k,n]
// A f32 [K x M] row-major (ws, per-g), B = state f32 [K x DD] (per-b)
// OUT_PER_B=false: C per-g (K3, w). OUT_PER_B=true: C per-b (K5, out).
template<bool OUT_PER_B>
__global__ __launch_bounds__(256) void k_tn(
    const float* __restrict__ A,
    const float* __restrict__ B,
    float* __restrict__ C,
    int M, int K, size_t strideA, size_t strideB, size_t strideC, int b0)
{
    __shared__ float As[32][68];
    __shared__ float Bs[32][68];
    const int g = blockIdx.z, b = b0 + g;
    const int m0 = blockIdx.y * 64;
    const int n0 = blockIdx.x * 64;
    const int tid = threadIdx.x;
    const float* Ag = A + (size_t)g * strideA;
    const float* Bb = B + (size_t)b * strideB;
    const int kk8 = tid >> 3;          // 0..31
    const int cp8 = (tid & 7) * 8;     // 0..56
    const int ty = tid >> 4, tx = tid & 15;
    float acc[4][4] = {};
    for (int k0 = 0; k0 < K; k0 += 32) {
        const float* ap = Ag + (size_t)(k0 + kk8) * M + m0 + cp8;
        const float* bp = Bb + (size_t)(k0 + kk8) * DD + n0 + cp8;
        float4 a0 = *reinterpret_cast<const float4*>(ap);
        float4 a1 = *reinterpret_cast<const float4*>(ap + 4);
        float4 b0v = *reinterpret_cast<const float4*>(bp);
        float4 b1v = *reinterpret_cast<const float4*>(bp + 4);
        __syncthreads();
        *reinterpret_cast<float4*>(&As[kk8][cp8])     = a0;
        *reinterpret_cast<float4*>(&As[kk8][cp8 + 4]) = a1;
        *reinterpret_cast<float4*>(&Bs[kk8][cp8])     = b0v;
        *reinterpret_cast<float4*>(&Bs[kk8][cp8 + 4]) = b1v;
        __syncthreads();
        #pragma unroll
        for (int kk = 0; kk < 32; ++kk) {
            float4 a4 = *reinterpret_cast<const float4*>(&As[kk][ty * 4]);
            float4 b4 = *reinterpret_cast<const float4*>(&Bs[kk][tx * 4]);
            float ar[4] = {a4.x, a4.y, a4.z, a4.w};
            float br[4] = {b4.x, b4.y, b4.z, b4.w};
            #pragma unroll
            for (int i = 0; i < 4; ++i)
                #pragma unroll
                for (int j = 0; j < 4; ++j)
                    acc[i][j] = fmaf(ar[i], br[j], acc[i][j]);
        }
    }
    float* Cg = C + (size_t)(OUT_PER_B ? b : g) * strideC;
    #pragma unroll
    for (int i = 0; i < 4; ++i)
        #pragma unroll
        for (int j = 0; j < 4; ++j)
            Cg[(size_t)(m0 + ty * 4 + i) * DD + n0 + tx * 4 + j] = acc[i][j];
}

// ---------------- K4: softmax over t (rows) per column d, masked rows -> 0, in place.
__global__ __launch_bounds__(256) void k4_softmax_t(
    float* __restrict__ w, const int* __restrict__ src, int b0)
{
    const int g = blockIdx.y, b = b0 + g;
    const int dc = threadIdx.x & 31;
    const int d = blockIdx.x * 32 + dc;
    const int tl = threadIdx.x >> 5; // 0..7
    float* base = w + (size_t)g * TT * DD + d;
    const int* sb = src + b * SS;
    float m = -INFINITY, l = 0.f;
    for (int t = tl; t < TT; t += 8) {
        if (sb[t] == 0) continue;
        float v = base[(size_t)t * DD];
        if (v > m) { l = l * __expf(m - v) + 1.f; m = v; }
        else       { l += __expf(v - m); }
    }
    __shared__ float sm[8][32], sv[8][32];
    sm[tl][dc] = m; sv[tl][dc] = l;
    __syncthreads();
    float M = sm[0][dc];
    #pragma unroll
    for (int i = 1; i < 8; ++i) M = fmaxf(M, sm[i][dc]);
    float L = 0.f;
    #pragma unroll
    for (int i = 0; i < 8; ++i) {
        float mi = sm[i][dc];
        if (mi > -INFINITY) L += sv[i][dc] * __expf(mi - M);
    }
    float inv = 1.f / L;
    for (int t = tl; t < TT; t += 8) {
        size_t off = (size_t)t * DD;
        base[off] = (sb[t] == 0) ? 0.f : __expf(base[off] - M) * inv;
    }
}

extern "C" void kernel_launch(void* const* d_in, const int* in_sizes, int n_in,
                              void* d_out, int out_size, void* d_ws, size_t ws_size,
                              hipStream_t stream)
{
    const float* state = (const float*)d_in[0];
    const float* x     = (const float*)d_in[1];
    const int* src     = (const int*)d_in[2];
    float* out         = (float*)d_out;

    const size_t perBatchFloats = (size_t)SS * TT + (size_t)TT * DD;
    int G = 8;
    while (G > 1 && (size_t)G * perBatchFloats * 4 > ws_size) G >>= 1;

    float* scores = (float*)d_ws;
    float* w      = scores + (size_t)G * SS * TT;

    for (int b0 = 0; b0 < NB; b0 += G) {
        dim3 g1(TT / 64, SS / 64, G);
        k1_scores<<<g1, 256, 0, stream>>>(state, x, src, scores, b0);

        k2_softmax_s<<<dim3(TT / 64, G), 256, 0, stream>>>(scores);

        dim3 g3(DD / 64, TT / 64, G);
        k_tn<false><<<g3, 256, 0, stream>>>(scores, state, w,
                                            TT, SS, (size_t)SS * TT, (size_t)SS * DD,
                                            (size_t)TT * DD, b0);

        k4_softmax_t<<<dim3(DD / 32, G), 256, 0, stream>>>(w, src, b0);

        dim3 g5(DD / 64, DD / 64, G);
        k_tn<true><<<g5, 256, 0, stream>>>(w, state, out,
                                           DD, TT, (size_t)TT * DD, (size_t)SS * DD,
                                           (size_t)DD * DD, b0);
    }
}

// Round 3
// 546.491 us; speedup vs baseline: 5.1229x; 5.1229x over previous
//
#include <hip/hip_runtime.h>
#include <hip/hip_bf16.h>

#define SS 2048
#define TT 2048
#define DD 1024
#define NB 8

typedef __attribute__((ext_vector_type(8))) short short8v;     // MFMA bf16 operand (8 bf16)
typedef __attribute__((ext_vector_type(8))) unsigned short us8;
typedef __attribute__((ext_vector_type(4))) unsigned short us4;
typedef __attribute__((ext_vector_type(4))) float f32x4;

__device__ __forceinline__ float bf2f(unsigned short u) {
    union { unsigned int i; float f; } v; v.i = ((unsigned int)u) << 16; return v.f;
}
__device__ __forceinline__ unsigned short f2bf(float f) {
    union { float f; unsigned int i; } v; v.f = f;
    unsigned int x = v.i;
    return (unsigned short)((x + 0x7fffu + ((x >> 16) & 1u)) >> 16);
}

// ============ stateT[d][s] (bf16) = state[s][d] (f32), per g ============
__global__ __launch_bounds__(256) void transpose_k(
    const float* __restrict__ in, unsigned short* __restrict__ outT,
    size_t sIn, size_t sOut)
{
    __shared__ float t[64][65];
    const int g = blockIdx.z;
    const float* I = in + g * sIn;            // [SS][DD]
    unsigned short* O = outT + g * sOut;      // [DD][SS]
    const int s0 = blockIdx.x * 64, d0 = blockIdx.y * 64;
    const int tid = threadIdx.x;
    #pragma unroll
    for (int i = 0; i < 4; ++i) {
        int slot = tid + i * 256;
        int rr = slot >> 4, rc = (slot & 15) * 4;
        float4 v = *reinterpret_cast<const float4*>(I + (size_t)(s0 + rr) * DD + d0 + rc);
        t[rr][rc + 0] = v.x; t[rr][rc + 1] = v.y; t[rr][rc + 2] = v.z; t[rr][rc + 3] = v.w;
    }
    __syncthreads();
    #pragma unroll
    for (int i = 0; i < 4; ++i) {
        int slot = tid + i * 256;
        int dr = slot >> 4, sidx = (slot & 15) * 4;
        us4 o;
        #pragma unroll
        for (int j = 0; j < 4; ++j) o[j] = f2bf(t[sidx + j][dr]);
        *reinterpret_cast<us4*>(O + (size_t)(d0 + dr) * SS + s0 + sidx) = o;
    }
}

// ============ K1: split-bf16 NT GEMM, C[m][n] = sum_k A[m,k]*B[n,k], fp32 in/out ====
__global__ __launch_bounds__(256) void gemm_nt_split(
    const float* __restrict__ A, const float* __restrict__ B, float* __restrict__ C,
    int lda, int ldb, int ldc, int K, size_t sA, size_t sB, size_t sC)
{
    __shared__ unsigned short Ah[128 * 40], Al[128 * 40], Bh[128 * 40], Bl[128 * 40];
    const int g = blockIdx.z;
    const float* Ag = A + g * sA;
    const float* Bg = B + g * sB;
    const int m0 = blockIdx.y * 128, n0 = blockIdx.x * 128;
    const int tid = threadIdx.x, lane = tid & 63, wid = tid >> 6;
    const int wm = (wid >> 1) * 64, wn = (wid & 1) * 64;
    const int lrow = lane & 15, lk8 = (lane >> 4) * 8;
    const int r0 = tid >> 3, c0 = (tid & 7) * 4;   // 4 slots: rows r0+{0,32,64,96}
    f32x4 acc[4][4] = {};
    for (int k0 = 0; k0 < K; k0 += 32) {
        float4 va[4], vb[4];
        #pragma unroll
        for (int i = 0; i < 4; ++i) {
            va[i] = *reinterpret_cast<const float4*>(Ag + (size_t)(m0 + r0 + i * 32) * lda + k0 + c0);
            vb[i] = *reinterpret_cast<const float4*>(Bg + (size_t)(n0 + r0 + i * 32) * ldb + k0 + c0);
        }
        __syncthreads();
        #pragma unroll
        for (int i = 0; i < 4; ++i) {
            int r = r0 + i * 32;
            float av[4] = {va[i].x, va[i].y, va[i].z, va[i].w};
            float bv[4] = {vb[i].x, vb[i].y, vb[i].z, vb[i].w};
            us4 h_a, l_a, h_b, l_b;
            #pragma unroll
            for (int j = 0; j < 4; ++j) {
                unsigned short ha = f2bf(av[j]); h_a[j] = ha; l_a[j] = f2bf(av[j] - bf2f(ha));
                unsigned short hb = f2bf(bv[j]); h_b[j] = hb; l_b[j] = f2bf(bv[j] - bf2f(hb));
            }
            *reinterpret_cast<us4*>(&Ah[r * 40 + c0]) = h_a;
            *reinterpret_cast<us4*>(&Al[r * 40 + c0]) = l_a;
            *reinterpret_cast<us4*>(&Bh[r * 40 + c0]) = h_b;
            *reinterpret_cast<us4*>(&Bl[r * 40 + c0]) = l_b;
        }
        __syncthreads();
        short8v a_h[4], a_l[4];
        #pragma unroll
        for (int mi = 0; mi < 4; ++mi) {
            a_h[mi] = *reinterpret_cast<const short8v*>(&Ah[(wm + mi * 16 + lrow) * 40 + lk8]);
            a_l[mi] = *reinterpret_cast<const short8v*>(&Al[(wm + mi * 16 + lrow) * 40 + lk8]);
        }
        #pragma unroll
        for (int ni = 0; ni < 4; ++ni) {
            short8v b_h = *reinterpret_cast<const short8v*>(&Bh[(wn + ni * 16 + lrow) * 40 + lk8]);
            short8v b_l = *reinterpret_cast<const short8v*>(&Bl[(wn + ni * 16 + lrow) * 40 + lk8]);
            #pragma unroll
            for (int mi = 0; mi < 4; ++mi) {
                acc[mi][ni] = __builtin_amdgcn_mfma_f32_16x16x32_bf16(a_h[mi], b_h, acc[mi][ni], 0, 0, 0);
                acc[mi][ni] = __builtin_amdgcn_mfma_f32_16x16x32_bf16(a_h[mi], b_l, acc[mi][ni], 0, 0, 0);
                acc[mi][ni] = __builtin_amdgcn_mfma_f32_16x16x32_bf16(a_l[mi], b_h, acc[mi][ni], 0, 0, 0);
            }
        }
    }
    const int orow = (lane >> 4) * 4, ocol = lane & 15;
    float* Cg = C + g * sC;
    #pragma unroll
    for (int mi = 0; mi < 4; ++mi)
        #pragma unroll
        for (int ni = 0; ni < 4; ++ni)
            #pragma unroll
            for (int r = 0; r < 4; ++r)
                Cg[(size_t)(m0 + wm + mi * 16 + orow + r) * ldc + (n0 + wn + ni * 16 + ocol)] = acc[mi][ni][r];
}

// ============ K3/K5: plain bf16 NT GEMM ============
template<int OUT_BF16>
__global__ __launch_bounds__(256) void gemm_nt_bf16(
    const unsigned short* __restrict__ A, const unsigned short* __restrict__ B,
    void* __restrict__ C, int lda, int ldb, int ldc, int K,
    size_t sA, size_t sB, size_t sC)
{
    __shared__ unsigned short As[128 * 40];
    __shared__ unsigned short Bs[128 * 40];
    const int g = blockIdx.z;
    const unsigned short* Ag = A + g * sA;
    const unsigned short* Bg = B + g * sB;
    const int m0 = blockIdx.y * 128, n0 = blockIdx.x * 128;
    const int tid = threadIdx.x, lane = tid & 63, wid = tid >> 6;
    const int wm = (wid >> 1) * 64, wn = (wid & 1) * 64;
    const int lrow = lane & 15, lk8 = (lane >> 4) * 8;
    const int r0 = tid >> 2, c0 = (tid & 3) * 8;   // 2 slots: rows r0, r0+64
    f32x4 acc[4][4] = {};
    for (int k0 = 0; k0 < K; k0 += 32) {
        us8 av0 = *reinterpret_cast<const us8*>(Ag + (size_t)(m0 + r0) * lda + k0 + c0);
        us8 av1 = *reinterpret_cast<const us8*>(Ag + (size_t)(m0 + r0 + 64) * lda + k0 + c0);
        us8 bv0 = *reinterpret_cast<const us8*>(Bg + (size_t)(n0 + r0) * ldb + k0 + c0);
        us8 bv1 = *reinterpret_cast<const us8*>(Bg + (size_t)(n0 + r0 + 64) * ldb + k0 + c0);
        __syncthreads();
        *reinterpret_cast<us8*>(&As[r0 * 40 + c0]) = av0;
        *reinterpret_cast<us8*>(&As[(r0 + 64) * 40 + c0]) = av1;
        *reinterpret_cast<us8*>(&Bs[r0 * 40 + c0]) = bv0;
        *reinterpret_cast<us8*>(&Bs[(r0 + 64) * 40 + c0]) = bv1;
        __syncthreads();
        short8v a[4];
        #pragma unroll
        for (int mi = 0; mi < 4; ++mi)
            a[mi] = *reinterpret_cast<const short8v*>(&As[(wm + mi * 16 + lrow) * 40 + lk8]);
        #pragma unroll
        for (int ni = 0; ni < 4; ++ni) {
            short8v b = *reinterpret_cast<const short8v*>(&Bs[(wn + ni * 16 + lrow) * 40 + lk8]);
            #pragma unroll
            for (int mi = 0; mi < 4; ++mi)
                acc[mi][ni] = __builtin_amdgcn_mfma_f32_16x16x32_bf16(a[mi], b, acc[mi][ni], 0, 0, 0);
        }
    }
    const int orow = (lane >> 4) * 4, ocol = lane & 15;
    if (OUT_BF16) {
        unsigned short* Cg = (unsigned short*)C + g * sC;
        #pragma unroll
        for (int mi = 0; mi < 4; ++mi)
            #pragma unroll
            for (int ni = 0; ni < 4; ++ni)
                #pragma unroll
                for (int r = 0; r < 4; ++r)
                    Cg[(size_t)(m0 + wm + mi * 16 + orow + r) * ldc + (n0 + wn + ni * 16 + ocol)] = f2bf(acc[mi][ni][r]);
    } else {
        float* Cg = (float*)C + g * sC;
        #pragma unroll
        for (int mi = 0; mi < 4; ++mi)
            #pragma unroll
            for (int ni = 0; ni < 4; ++ni)
                #pragma unroll
                for (int r = 0; r < 4; ++r)
                    Cg[(size_t)(m0 + wm + mi * 16 + orow + r) * ldc + (n0 + wn + ni * 16 + ocol)] = acc[mi][ni][r];
    }
}

// ============ K2: row softmax over s (masked), scoresT fp32 -> pT bf16 in place ===
__global__ __launch_bounds__(256) void softmax1_k(
    float* __restrict__ regA, const int* __restrict__ src, int b0, size_t sA)
{
    const int t = blockIdx.x, g = blockIdx.y, b = b0 + g, tid = threadIdx.x;
    float* row = regA + g * sA + (size_t)t * SS;
    const int* sb = src + (size_t)b * SS;
    float v[8]; int msk[8];
    float m = -1e30f;
    #pragma unroll
    for (int i = 0; i < 8; ++i) {
        int s = i * 256 + tid;
        msk[i] = (sb[s] == 0);
        v[i] = msk[i] ? -1e30f : row[s];
        m = fmaxf(m, v[i]);
    }
    #pragma unroll
    for (int o = 32; o > 0; o >>= 1) m = fmaxf(m, __shfl_xor(m, o, 64));
    __shared__ float shm[4], shl[4];
    if ((tid & 63) == 0) shm[tid >> 6] = m;
    __syncthreads();
    float M = fmaxf(fmaxf(shm[0], shm[1]), fmaxf(shm[2], shm[3]));
    float l = 0.f;
    #pragma unroll
    for (int i = 0; i < 8; ++i) if (!msk[i]) { v[i] = __expf(v[i] - M); l += v[i]; }
    #pragma unroll
    for (int o = 32; o > 0; o >>= 1) l += __shfl_xor(l, o, 64);
    if ((tid & 63) == 0) shl[tid >> 6] = l;
    __syncthreads();
    float inv = 1.f / (shl[0] + shl[1] + shl[2] + shl[3]);
    unsigned short* prow = (unsigned short*)row;   // in-place, this block owns the row
    #pragma unroll
    for (int i = 0; i < 8; ++i) {
        int s = i * 256 + tid;
        prow[s] = msk[i] ? 0 : f2bf(v[i] * inv);
    }
}

// ============ K4: row softmax over t (masked), wT bf16 -> attnT bf16 ============
__global__ __launch_bounds__(256) void softmax2_k(
    const unsigned short* __restrict__ wT, unsigned short* __restrict__ attnT,
    const int* __restrict__ src, int b0, size_t sW, size_t sAt)
{
    const int e = blockIdx.x, g = blockIdx.y, b = b0 + g, tid = threadIdx.x;
    const unsigned short* row = wT + g * sW + (size_t)e * TT;
    unsigned short* orow = attnT + g * sAt + (size_t)e * TT;
    const int* sb = src + (size_t)b * SS;
    float v[8]; int msk[8];
    float m = -1e30f;
    #pragma unroll
    for (int i = 0; i < 8; ++i) {
        int t = i * 256 + tid;
        msk[i] = (sb[t] == 0);
        v[i] = msk[i] ? -1e30f : bf2f(row[t]);
        m = fmaxf(m, v[i]);
    }
    #pragma unroll
    for (int o = 32; o > 0; o >>= 1) m = fmaxf(m, __shfl_xor(m, o, 64));
    __shared__ float shm[4], shl[4];
    if ((tid & 63) == 0) shm[tid >> 6] = m;
    __syncthreads();
    float M = fmaxf(fmaxf(shm[0], shm[1]), fmaxf(shm[2], shm[3]));
    float l = 0.f;
    #pragma unroll
    for (int i = 0; i < 8; ++i) if (!msk[i]) { v[i] = __expf(v[i] - M); l += v[i]; }
    #pragma unroll
    for (int o = 32; o > 0; o >>= 1) l += __shfl_xor(l, o, 64);
    if ((tid & 63) == 0) shl[tid >> 6] = l;
    __syncthreads();
    float inv = 1.f / (shl[0] + shl[1] + shl[2] + shl[3]);
    #pragma unroll
    for (int i = 0; i < 8; ++i) {
        int t = i * 256 + tid;
        orow[t] = msk[i] ? 0 : f2bf(v[i] * inv);
    }
}

extern "C" void kernel_launch(void* const* d_in, const int* in_sizes, int n_in,
                              void* d_out, int out_size, void* d_ws, size_t ws_size,
                              hipStream_t stream)
{
    const float* state = (const float*)d_in[0];
    const float* x     = (const float*)d_in[1];
    const int* src     = (const int*)d_in[2];
    float* out         = (float*)d_out;

    const size_t SD = (size_t)SS * DD;                 // f32 elems per batch (state/x)
    const size_t perA_b = (size_t)SS * TT * 4;         // 16 MB: scoresT / pT / attnT
    const size_t perB_b = (size_t)DD * SS * 2;         // 4 MB: stateT
    const size_t perC_b = (size_t)DD * TT * 2;         // 4 MB: wT
    const size_t perBatch = perA_b + perB_b + perC_b;  // 24 MB

    int G = 8;
    while (G > 1 && (size_t)G * perBatch > ws_size) G >>= 1;

    char* base = (char*)d_ws;
    float* regA          = (float*)base;                                  // G x 16MB
    unsigned short* regB = (unsigned short*)(base + (size_t)G * perA_b);  // G x 4MB
    unsigned short* regC = (unsigned short*)(base + (size_t)G * (perA_b + perB_b));

    const size_t sA_f32 = (size_t)SS * TT;       // floats per g in regA
    const size_t sA_us  = (size_t)SS * TT * 2;   // ushorts per g in regA
    const size_t sB_us  = (size_t)DD * SS;       // ushorts per g in regB/regC

    for (int b0 = 0; b0 < NB; b0 += G) {
        // stateT[d][s] bf16
        transpose_k<<<dim3(SS / 64, DD / 64, G), 256, 0, stream>>>(
            state + (size_t)b0 * SD, regB, SD, sB_us);

        // K1: scoresT[t][s] = x . state^T  (split bf16, fp32 out)
        gemm_nt_split<<<dim3(SS / 128, TT / 128, G), 256, 0, stream>>>(
            x + (size_t)b0 * SD, state + (size_t)b0 * SD, regA,
            DD, DD, SS, DD, SD, SD, sA_f32);

        // K2: softmax over s per row t; pT bf16 in place (row stride SS*2 ushorts)
        softmax1_k<<<dim3(TT, G), 256, 0, stream>>>(regA, src, b0, sA_f32);

        // K3: wT[d][t] = stateT . pT^T  (bf16 out)
        gemm_nt_bf16<1><<<dim3(TT / 128, DD / 128, G), 256, 0, stream>>>(
            regB, (const unsigned short*)regA, regC,
            SS, SS * 2, TT, SS, sB_us, sA_us, sB_us);

        // K4: softmax over t per row e (d); attnT bf16 into regA (pT dead)
        softmax2_k<<<dim3(DD, G), 256, 0, stream>>>(
            regC, (unsigned short*)regA, src, b0, sB_us, sA_us);

        // K5: out[e][d] = attnT . stateT^T  (fp32 out, direct to d_out)
        gemm_nt_bf16<0><<<dim3(DD / 128, DD / 128, G), 256, 0, stream>>>(
            (const unsigned short*)regA, regB, out + (size_t)b0 * DD * DD,
            TT, SS, DD, TT, sA_us, sB_us, (size_t)DD * DD);
    }
}

// Round 4
// 457.448 us; speedup vs baseline: 6.1200x; 1.1947x over previous
//
#include <hip/hip_runtime.h>
#include <hip/hip_bf16.h>

#define SS 2048
#define TT 2048
#define DD 1024
#define NB 8

typedef __attribute__((ext_vector_type(8))) short short8v;     // MFMA bf16 operand
typedef __attribute__((ext_vector_type(8))) unsigned short us8;
typedef __attribute__((ext_vector_type(4))) unsigned short us4;
typedef __attribute__((ext_vector_type(4))) float f32x4;

__device__ __forceinline__ float bf2f(unsigned short u) {
    union { unsigned int i; float f; } v; v.i = ((unsigned int)u) << 16; return v.f;
}
__device__ __forceinline__ unsigned short f2bf(float f) {
    union { float f; unsigned int i; } v; v.f = f;
    unsigned int x = v.i;
    return (unsigned short)((x + 0x7fffu + ((x >> 16) & 1u)) >> 16);
}

// ============ xbf = bf16(x), elementwise ============
__global__ __launch_bounds__(256) void conv_k(
    const float* __restrict__ in, unsigned short* __restrict__ outv, size_t n)
{
    size_t i = ((size_t)blockIdx.x * 256 + threadIdx.x) * 8;
    const size_t stride = (size_t)gridDim.x * 256 * 8;
    for (; i < n; i += stride) {
        float4 a = *reinterpret_cast<const float4*>(in + i);
        float4 b = *reinterpret_cast<const float4*>(in + i + 4);
        us8 o;
        o[0] = f2bf(a.x); o[1] = f2bf(a.y); o[2] = f2bf(a.z); o[3] = f2bf(a.w);
        o[4] = f2bf(b.x); o[5] = f2bf(b.y); o[6] = f2bf(b.z); o[7] = f2bf(b.w);
        *reinterpret_cast<us8*>(outv + i) = o;
    }
}

// ============ stateT[d][s] bf16 + statebf[s][d] bf16 from state f32 ============
__global__ __launch_bounds__(256) void transpose_k(
    const float* __restrict__ in, unsigned short* __restrict__ outT,
    unsigned short* __restrict__ outB, size_t sIn, size_t sOutT, size_t sOutB)
{
    __shared__ float t[64][65];
    const int g = blockIdx.z;
    const float* I = in + g * sIn;            // [SS][DD]
    unsigned short* OT = outT + g * sOutT;    // [DD][SS]
    unsigned short* OB = outB + g * sOutB;    // [SS][DD]
    const int s0 = blockIdx.x * 64, d0 = blockIdx.y * 64;
    const int tid = threadIdx.x;
    #pragma unroll
    for (int i = 0; i < 4; ++i) {
        int slot = tid + i * 256;
        int rr = slot >> 4, rc = (slot & 15) * 4;
        float4 v = *reinterpret_cast<const float4*>(I + (size_t)(s0 + rr) * DD + d0 + rc);
        t[rr][rc + 0] = v.x; t[rr][rc + 1] = v.y; t[rr][rc + 2] = v.z; t[rr][rc + 3] = v.w;
        us4 o; o[0] = f2bf(v.x); o[1] = f2bf(v.y); o[2] = f2bf(v.z); o[3] = f2bf(v.w);
        *reinterpret_cast<us4*>(OB + (size_t)(s0 + rr) * DD + d0 + rc) = o;
    }
    __syncthreads();
    #pragma unroll
    for (int i = 0; i < 4; ++i) {
        int slot = tid + i * 256;
        int dr = slot >> 4, sidx = (slot & 15) * 4;
        us4 o;
        #pragma unroll
        for (int j = 0; j < 4; ++j) o[j] = f2bf(t[sidx + j][dr]);
        *reinterpret_cast<us4*>(OT + (size_t)(d0 + dr) * SS + s0 + sidx) = o;
    }
}

// ============ NT bf16 GEMM, m97 structure: global_load_lds + 2-barrier ============
// C[m][n] = sum_k A[m,k]*B[n,k].  128x128 tile, BK=32, 4 waves, 4x4 frags/wave.
template<int OUT_F32>
__global__ __launch_bounds__(256) void gemm_nt(
    const unsigned short* __restrict__ A, const unsigned short* __restrict__ B,
    void* __restrict__ C, int lda, int ldb, int ldc, int K,
    size_t sA, size_t sB, size_t sC)
{
    __shared__ unsigned short As[128 * 32];
    __shared__ unsigned short Bs[128 * 32];
    const int g = blockIdx.z;
    const unsigned short* Ag = A + g * sA;
    const unsigned short* Bg = B + g * sB;
    const int m0 = blockIdx.y * 128, n0 = blockIdx.x * 128;
    const int tid = threadIdx.x, lane = tid & 63, wid = tid >> 6;
    const int wm = (wid >> 1) * 64, wn = (wid & 1) * 64;
    const int lr16 = lane & 15, lk8 = (lane >> 4) * 8;
    // staging: wave wid covers rows [wid*32, wid*32+32), 2 issues of 16 rows each
    const int srow = wid * 32 + (lane >> 2);
    const int scol = (lane & 3) * 8;
    f32x4 acc[4][4] = {};
    for (int k0 = 0; k0 < K; k0 += 32) {
        #pragma unroll
        for (int i = 0; i < 2; ++i) {
            const unsigned short* ga = Ag + (size_t)(m0 + srow + i * 16) * lda + k0 + scol;
            const unsigned short* gb = Bg + (size_t)(n0 + srow + i * 16) * ldb + k0 + scol;
            __builtin_amdgcn_global_load_lds(
                (const __attribute__((address_space(1))) unsigned int*)ga,
                (__attribute__((address_space(3))) unsigned int*)&As[(wid * 32 + i * 16) * 32],
                16, 0, 0);
            __builtin_amdgcn_global_load_lds(
                (const __attribute__((address_space(1))) unsigned int*)gb,
                (__attribute__((address_space(3))) unsigned int*)&Bs[(wid * 32 + i * 16) * 32],
                16, 0, 0);
        }
        __syncthreads();   // compiler drains vmcnt(0) before barrier
        short8v a[4], bb[4];
        #pragma unroll
        for (int mi = 0; mi < 4; ++mi)
            a[mi] = *reinterpret_cast<const short8v*>(&As[(wm + mi * 16 + lr16) * 32 + lk8]);
        #pragma unroll
        for (int ni = 0; ni < 4; ++ni)
            bb[ni] = *reinterpret_cast<const short8v*>(&Bs[(wn + ni * 16 + lr16) * 32 + lk8]);
        #pragma unroll
        for (int ni = 0; ni < 4; ++ni)
            #pragma unroll
            for (int mi = 0; mi < 4; ++mi)
                acc[mi][ni] = __builtin_amdgcn_mfma_f32_16x16x32_bf16(a[mi], bb[ni], acc[mi][ni], 0, 0, 0);
        __syncthreads();   // LDS free before next stage
    }
    const int orow = (lane >> 4) * 4, ocol = lane & 15;
    if (OUT_F32) {
        float* Cg = (float*)C + g * sC;
        #pragma unroll
        for (int mi = 0; mi < 4; ++mi)
            #pragma unroll
            for (int ni = 0; ni < 4; ++ni)
                #pragma unroll
                for (int r = 0; r < 4; ++r)
                    Cg[(size_t)(m0 + wm + mi * 16 + orow + r) * ldc + (n0 + wn + ni * 16 + ocol)] = acc[mi][ni][r];
    } else {
        unsigned short* Cg = (unsigned short*)C + g * sC;
        #pragma unroll
        for (int mi = 0; mi < 4; ++mi)
            #pragma unroll
            for (int ni = 0; ni < 4; ++ni)
                #pragma unroll
                for (int r = 0; r < 4; ++r)
                    Cg[(size_t)(m0 + wm + mi * 16 + orow + r) * ldc + (n0 + wn + ni * 16 + ocol)] = f2bf(acc[mi][ni][r]);
    }
}

// ============ K2: row softmax over s + fp32 window refinement, bf16 in place =====
__global__ __launch_bounds__(256) void softmax1_k(
    unsigned short* __restrict__ P, const float* __restrict__ x,
    const float* __restrict__ state, const int* __restrict__ src,
    int b0, size_t sP)
{
    const int t = blockIdx.x, g = blockIdx.y, b = b0 + g, tid = threadIdx.x;
    const int lane = tid & 63, wid = tid >> 6;
    unsigned short* row = P + g * sP + (size_t)t * SS;
    const int* sb = src + (size_t)b * SS;
    __shared__ float redA[4], redB[4];
    __shared__ int cnt, list[96];
    __shared__ float corr[96];
    float v[8]; int msk[8];
    float m = -1e30f;
    #pragma unroll
    for (int i = 0; i < 8; ++i) {
        int s = i * 256 + tid;
        msk[i] = (sb[s] == 0);
        v[i] = msk[i] ? -1e30f : bf2f(row[s]);
        m = fmaxf(m, v[i]);
    }
    #pragma unroll
    for (int o = 32; o > 0; o >>= 1) m = fmaxf(m, __shfl_xor(m, o, 64));
    if (lane == 0) redA[wid] = m;
    if (tid == 0) cnt = 0;
    __syncthreads();
    const float M = fmaxf(fmaxf(redA[0], redA[1]), fmaxf(redA[2], redA[3]));
    __syncthreads();
    // flag entries within 16 of max (bf16 dot error << 16)
    #pragma unroll
    for (int i = 0; i < 8; ++i) {
        if (!msk[i] && v[i] > M - 16.f) {
            int j = atomicAdd(&cnt, 1);
            if (j < 96) list[j] = i * 256 + tid;
        }
    }
    __syncthreads();
    const int n = min(cnt, 96);
    const float* xr = x + (size_t)b * SS * DD + (size_t)t * DD;
    const float4 a4 = reinterpret_cast<const float4*>(xr)[tid];
    for (int j = 0; j < n; ++j) {
        const float* sr = state + (size_t)b * SS * DD + (size_t)list[j] * DD;
        float4 c4 = reinterpret_cast<const float4*>(sr)[tid];
        float p = a4.x * c4.x + a4.y * c4.y + a4.z * c4.z + a4.w * c4.w;
        #pragma unroll
        for (int o = 32; o > 0; o >>= 1) p += __shfl_xor(p, o, 64);
        if (lane == 0) redA[wid] = p;
        __syncthreads();
        if (tid == 0) corr[j] = redA[0] + redA[1] + redA[2] + redA[3];
        __syncthreads();
    }
    // apply corrections
    for (int j = 0; j < n; ++j) {
        int s = list[j];
        if ((s & 255) == tid) v[s >> 8] = corr[j];
    }
    // final max + sum + write
    float m2 = -1e30f;
    #pragma unroll
    for (int i = 0; i < 8; ++i) m2 = fmaxf(m2, v[i]);
    #pragma unroll
    for (int o = 32; o > 0; o >>= 1) m2 = fmaxf(m2, __shfl_xor(m2, o, 64));
    if (lane == 0) redA[wid] = m2;
    __syncthreads();
    const float M2 = fmaxf(fmaxf(redA[0], redA[1]), fmaxf(redA[2], redA[3]));
    float l = 0.f;
    #pragma unroll
    for (int i = 0; i < 8; ++i) if (!msk[i]) { v[i] = __expf(v[i] - M2); l += v[i]; }
    #pragma unroll
    for (int o = 32; o > 0; o >>= 1) l += __shfl_xor(l, o, 64);
    if (lane == 0) redB[wid] = l;
    __syncthreads();
    const float inv = 1.f / (redB[0] + redB[1] + redB[2] + redB[3]);
    #pragma unroll
    for (int i = 0; i < 8; ++i) {
        int s = i * 256 + tid;
        row[s] = msk[i] ? 0 : f2bf(v[i] * inv);
    }
}

// ============ K4: row softmax over t (masked), wT bf16 -> attnT bf16 ============
__global__ __launch_bounds__(256) void softmax2_k(
    const unsigned short* __restrict__ wT, unsigned short* __restrict__ attnT,
    const int* __restrict__ src, int b0, size_t sW, size_t sAt)
{
    const int e = blockIdx.x, g = blockIdx.y, b = b0 + g, tid = threadIdx.x;
    const int lane = tid & 63, wid = tid >> 6;
    const unsigned short* row = wT + g * sW + (size_t)e * TT;
    unsigned short* orow = attnT + g * sAt + (size_t)e * TT;
    const int* sb = src + (size_t)b * SS;
    __shared__ float shm[4], shl[4];
    float v[8]; int msk[8];
    float m = -1e30f;
    #pragma unroll
    for (int i = 0; i < 8; ++i) {
        int tt = i * 256 + tid;
        msk[i] = (sb[tt] == 0);
        v[i] = msk[i] ? -1e30f : bf2f(row[tt]);
        m = fmaxf(m, v[i]);
    }
    #pragma unroll
    for (int o = 32; o > 0; o >>= 1) m = fmaxf(m, __shfl_xor(m, o, 64));
    if (lane == 0) shm[wid] = m;
    __syncthreads();
    const float M = fmaxf(fmaxf(shm[0], shm[1]), fmaxf(shm[2], shm[3]));
    float l = 0.f;
    #pragma unroll
    for (int i = 0; i < 8; ++i) if (!msk[i]) { v[i] = __expf(v[i] - M); l += v[i]; }
    #pragma unroll
    for (int o = 32; o > 0; o >>= 1) l += __shfl_xor(l, o, 64);
    if (lane == 0) shl[wid] = l;
    __syncthreads();
    const float inv = 1.f / (shl[0] + shl[1] + shl[2] + shl[3]);
    #pragma unroll
    for (int i = 0; i < 8; ++i) {
        int tt = i * 256 + tid;
        orow[tt] = msk[i] ? 0 : f2bf(v[i] * inv);
    }
}

extern "C" void kernel_launch(void* const* d_in, const int* in_sizes, int n_in,
                              void* d_out, int out_size, void* d_ws, size_t ws_size,
                              hipStream_t stream)
{
    const float* state = (const float*)d_in[0];
    const float* x     = (const float*)d_in[1];
    const int* src     = (const int*)d_in[2];
    float* out         = (float*)d_out;

    const size_t SD = (size_t)SS * DD;   // f32 elems per batch
    // per-batch ws: P 8MB + ST 4MB + W 4MB + XB 4MB + SB 4MB = 24MB
    const size_t perP  = (size_t)SS * TT * 2;
    const size_t perST = (size_t)DD * SS * 2;
    const size_t perW  = (size_t)DD * TT * 2;
    const size_t perXB = (size_t)SS * DD * 2;
    const size_t perSB = (size_t)SS * DD * 2;
    const size_t perBatch = perP + perST + perW + perXB + perSB;

    int G = 8;
    while (G > 1 && (size_t)G * perBatch > ws_size) G >>= 1;

    char* base = (char*)d_ws;
    unsigned short* P  = (unsigned short*)base;
    unsigned short* ST = (unsigned short*)(base + (size_t)G * perP);
    unsigned short* W  = (unsigned short*)(base + (size_t)G * (perP + perST));
    unsigned short* XB = (unsigned short*)(base + (size_t)G * (perP + perST + perW));
    unsigned short* SB = (unsigned short*)(base + (size_t)G * (perP + perST + perW + perXB));

    const size_t sP  = (size_t)SS * TT;   // elems per g
    const size_t sST = (size_t)DD * SS;
    const size_t sW  = (size_t)DD * TT;
    const size_t sXB = (size_t)SS * DD;

    for (int b0 = 0; b0 < NB; b0 += G) {
        // prep: xbf bf16; stateT + statebf bf16
        conv_k<<<2048, 256, 0, stream>>>(x + (size_t)b0 * SD, XB, (size_t)G * SD);
        transpose_k<<<dim3(SS / 64, DD / 64, G), 256, 0, stream>>>(
            state + (size_t)b0 * SD, ST, SB, SD, sST, sXB);

        // K1: scoresT[t][s] = xbf . statebf^T   (bf16 out into P)
        gemm_nt<0><<<dim3(SS / 128, TT / 128, G), 256, 0, stream>>>(
            XB, SB, P, DD, DD, SS, DD, sXB, sXB, sP);

        // K2: softmax over s per row t, with fp32 window refinement; pT in place
        softmax1_k<<<dim3(TT, G), 256, 0, stream>>>(P, x, state, src, b0, sP);

        // K3: wT[d][t] = stateT . pT^T   (bf16 out)
        gemm_nt<0><<<dim3(TT / 128, DD / 128, G), 256, 0, stream>>>(
            ST, P, W, SS, SS, TT, SS, sST, sP, sW);

        // K4: softmax over t per row e; attnT bf16 into P (pT dead)
        softmax2_k<<<dim3(DD, G), 256, 0, stream>>>(W, P, src, b0, sW, sP);

        // K5: out[e][d] = attnT . stateT^T   (fp32 out, direct)
        gemm_nt<1><<<dim3(DD / 128, DD / 128, G), 256, 0, stream>>>(
            P, ST, out + (size_t)b0 * DD * DD, TT, SS, DD, TT, sP, sST, (size_t)DD * DD);
    }
}

// Round 5
// 410.783 us; speedup vs baseline: 6.8153x; 1.1136x over previous
//
#include <hip/hip_runtime.h>
#include <hip/hip_bf16.h>

#define SS 2048
#define TT 2048
#define DD 1024
#define NB 8

typedef __attribute__((ext_vector_type(8))) short short8v;     // MFMA bf16 operand
typedef __attribute__((ext_vector_type(8))) unsigned short us8;
typedef __attribute__((ext_vector_type(4))) unsigned short us4;
typedef __attribute__((ext_vector_type(4))) float f32x4;

__device__ __forceinline__ float bf2f(unsigned short u) {
    union { unsigned int i; float f; } v; v.i = ((unsigned int)u) << 16; return v.f;
}
__device__ __forceinline__ unsigned short f2bf(float f) {
    union { float f; unsigned int i; } v; v.f = f;
    unsigned int x = v.i;
    return (unsigned short)((x + 0x7fffu + ((x >> 16) & 1u)) >> 16);
}

// ============ xbf = bf16(x), elementwise ============
__global__ __launch_bounds__(256) void conv_k(
    const float* __restrict__ in, unsigned short* __restrict__ outv, size_t n)
{
    size_t i = ((size_t)blockIdx.x * 256 + threadIdx.x) * 8;
    const size_t stride = (size_t)gridDim.x * 256 * 8;
    for (; i < n; i += stride) {
        float4 a = *reinterpret_cast<const float4*>(in + i);
        float4 b = *reinterpret_cast<const float4*>(in + i + 4);
        us8 o;
        o[0] = f2bf(a.x); o[1] = f2bf(a.y); o[2] = f2bf(a.z); o[3] = f2bf(a.w);
        o[4] = f2bf(b.x); o[5] = f2bf(b.y); o[6] = f2bf(b.z); o[7] = f2bf(b.w);
        *reinterpret_cast<us8*>(outv + i) = o;
    }
}

// ============ stateT[d][s] bf16 + statebf[s][d] bf16 from state f32 ============
__global__ __launch_bounds__(256) void transpose_k(
    const float* __restrict__ in, unsigned short* __restrict__ outT,
    unsigned short* __restrict__ outB, size_t sIn, size_t sOutT, size_t sOutB)
{
    __shared__ float t[64][65];
    const int g = blockIdx.z;
    const float* I = in + g * sIn;            // [SS][DD]
    unsigned short* OT = outT + g * sOutT;    // [DD][SS]
    unsigned short* OB = outB + g * sOutB;    // [SS][DD]
    const int s0 = blockIdx.x * 64, d0 = blockIdx.y * 64;
    const int tid = threadIdx.x;
    #pragma unroll
    for (int i = 0; i < 4; ++i) {
        int slot = tid + i * 256;
        int rr = slot >> 4, rc = (slot & 15) * 4;
        float4 v = *reinterpret_cast<const float4*>(I + (size_t)(s0 + rr) * DD + d0 + rc);
        t[rr][rc + 0] = v.x; t[rr][rc + 1] = v.y; t[rr][rc + 2] = v.z; t[rr][rc + 3] = v.w;
        us4 o; o[0] = f2bf(v.x); o[1] = f2bf(v.y); o[2] = f2bf(v.z); o[3] = f2bf(v.w);
        *reinterpret_cast<us4*>(OB + (size_t)(s0 + rr) * DD + d0 + rc) = o;
    }
    __syncthreads();
    #pragma unroll
    for (int i = 0; i < 4; ++i) {
        int slot = tid + i * 256;
        int dr = slot >> 4, sidx = (slot & 15) * 4;
        us4 o;
        #pragma unroll
        for (int j = 0; j < 4; ++j) o[j] = f2bf(t[sidx + j][dr]);
        *reinterpret_cast<us4*>(OT + (size_t)(d0 + dr) * SS + s0 + sidx) = o;
    }
}

// ============ NT bf16 GEMM: dbuf LDS + prefetch + T2 swizzle, BK=64 ============
// C[m][n] = sum_k A[m,k]*B[n,k]. 128x128 tile, 4 waves, 4x4 frags/wave.
// LDS row = 128B (64 bf16); 16B chunk c of row r lives at slot c^(r&7).
// Staged via global_load_lds (linear LDS dest) with inverse-swizzled global src.
template<int OUT_F32>
__global__ __launch_bounds__(256, 2) void gemm_nt(
    const unsigned short* __restrict__ A, const unsigned short* __restrict__ B,
    void* __restrict__ C, int lda, int ldb, int ldc, int K,
    size_t sA, size_t sB, size_t sC)
{
    __shared__ unsigned short As[2][128 * 64];
    __shared__ unsigned short Bs[2][128 * 64];
    const int g = blockIdx.z;
    const unsigned short* Ag = A + g * sA;
    const unsigned short* Bg = B + g * sB;
    const int m0 = blockIdx.y * 128, n0 = blockIdx.x * 128;
    const int tid = threadIdx.x, lane = tid & 63, wid = tid >> 6;
    const int wm = (wid >> 1) * 64, wn = (wid & 1) * 64;
    const int lr16 = lane & 15, lk = lane >> 4;           // frag row / k-chunk
    const int sr = wid * 32 + (lane >> 3);                // staging row base (j*8 added)
    const int sp = lane & 7;                              // staging slot

    f32x4 acc[4][4] = {};
    const int NT = K >> 6;

#define STAGE(buf, kt)                                                          \
    {                                                                           \
        const int k0 = (kt) << 6;                                               \
        _Pragma("unroll")                                                       \
        for (int j = 0; j < 4; ++j) {                                           \
            int r = sr + j * 8;                                                 \
            int c = sp ^ (r & 7);                                               \
            __builtin_amdgcn_global_load_lds(                                   \
                (const __attribute__((address_space(1))) unsigned int*)        \
                    (Ag + (size_t)(m0 + r) * lda + k0 + c * 8),                 \
                (__attribute__((address_space(3))) unsigned int*)              \
                    (&As[buf][(wid * 32 + j * 8) * 64]),                        \
                16, 0, 0);                                                      \
            __builtin_amdgcn_global_load_lds(                                   \
                (const __attribute__((address_space(1))) unsigned int*)        \
                    (Bg + (size_t)(n0 + r) * ldb + k0 + c * 8),                 \
                (__attribute__((address_space(3))) unsigned int*)              \
                    (&Bs[buf][(wid * 32 + j * 8) * 64]),                        \
                16, 0, 0);                                                      \
        }                                                                       \
    }

    int cur = 0;
    STAGE(0, 0);
    __syncthreads();
    for (int kt = 0; kt < NT; ++kt) {
        if (kt + 1 < NT) STAGE(cur ^ 1, kt + 1);
        #pragma unroll
        for (int ks = 0; ks < 2; ++ks) {
            short8v a[4], bb[4];
            const int c = ks * 4 + lk;
            #pragma unroll
            for (int mi = 0; mi < 4; ++mi) {
                int r = wm + mi * 16 + lr16;
                a[mi] = *reinterpret_cast<const short8v*>(&As[cur][r * 64 + (c ^ (r & 7)) * 8]);
            }
            #pragma unroll
            for (int ni = 0; ni < 4; ++ni) {
                int r = wn + ni * 16 + lr16;
                bb[ni] = *reinterpret_cast<const short8v*>(&Bs[cur][r * 64 + (c ^ (r & 7)) * 8]);
            }
            #pragma unroll
            for (int ni = 0; ni < 4; ++ni)
                #pragma unroll
                for (int mi = 0; mi < 4; ++mi)
                    acc[mi][ni] = __builtin_amdgcn_mfma_f32_16x16x32_bf16(a[mi], bb[ni], acc[mi][ni], 0, 0, 0);
        }
        __syncthreads();
        cur ^= 1;
    }
#undef STAGE

    const int orow = (lane >> 4) * 4, ocol = lane & 15;
    if (OUT_F32) {
        float* Cg = (float*)C + g * sC;
        #pragma unroll
        for (int mi = 0; mi < 4; ++mi)
            #pragma unroll
            for (int ni = 0; ni < 4; ++ni)
                #pragma unroll
                for (int r = 0; r < 4; ++r)
                    Cg[(size_t)(m0 + wm + mi * 16 + orow + r) * ldc + (n0 + wn + ni * 16 + ocol)] = acc[mi][ni][r];
    } else {
        unsigned short* Cg = (unsigned short*)C + g * sC;
        #pragma unroll
        for (int mi = 0; mi < 4; ++mi)
            #pragma unroll
            for (int ni = 0; ni < 4; ++ni)
                #pragma unroll
                for (int r = 0; r < 4; ++r)
                    Cg[(size_t)(m0 + wm + mi * 16 + orow + r) * ldc + (n0 + wn + ni * 16 + ocol)] = f2bf(acc[mi][ni][r]);
    }
}

// ============ K2: row softmax over s + fp32 window refinement, bf16 in place =====
__global__ __launch_bounds__(256) void softmax1_k(
    unsigned short* __restrict__ P, const float* __restrict__ x,
    const float* __restrict__ state, const int* __restrict__ src,
    int b0, size_t sP)
{
    const int t = blockIdx.x, g = blockIdx.y, b = b0 + g, tid = threadIdx.x;
    const int lane = tid & 63, wid = tid >> 6;
    unsigned short* row = P + g * sP + (size_t)t * SS;
    const int* sb = src + (size_t)b * SS;
    __shared__ float redA[4], redB[4];
    __shared__ int cnt, list[96];
    __shared__ float corr[96];
    float v[8]; int msk[8];
    float m = -1e30f;
    #pragma unroll
    for (int i = 0; i < 8; ++i) {
        int s = i * 256 + tid;
        msk[i] = (sb[s] == 0);
        v[i] = msk[i] ? -1e30f : bf2f(row[s]);
        m = fmaxf(m, v[i]);
    }
    #pragma unroll
    for (int o = 32; o > 0; o >>= 1) m = fmaxf(m, __shfl_xor(m, o, 64));
    if (lane == 0) redA[wid] = m;
    if (tid == 0) cnt = 0;
    __syncthreads();
    const float M = fmaxf(fmaxf(redA[0], redA[1]), fmaxf(redA[2], redA[3]));
    __syncthreads();
    // flag entries within 16 of max (bf16 dot error << 16)
    #pragma unroll
    for (int i = 0; i < 8; ++i) {
        if (!msk[i] && v[i] > M - 16.f) {
            int j = atomicAdd(&cnt, 1);
            if (j < 96) list[j] = i * 256 + tid;
        }
    }
    __syncthreads();
    const int n = min(cnt, 96);
    const float* xr = x + (size_t)b * SS * DD + (size_t)t * DD;
    const float4 a4 = reinterpret_cast<const float4*>(xr)[tid];
    for (int j = 0; j < n; ++j) {
        const float* sr = state + (size_t)b * SS * DD + (size_t)list[j] * DD;
        float4 c4 = reinterpret_cast<const float4*>(sr)[tid];
        float p = a4.x * c4.x + a4.y * c4.y + a4.z * c4.z + a4.w * c4.w;
        #pragma unroll
        for (int o = 32; o > 0; o >>= 1) p += __shfl_xor(p, o, 64);
        if (lane == 0) redA[wid] = p;
        __syncthreads();
        if (tid == 0) corr[j] = redA[0] + redA[1] + redA[2] + redA[3];
        __syncthreads();
    }
    // apply corrections
    for (int j = 0; j < n; ++j) {
        int s = list[j];
        if ((s & 255) == tid) v[s >> 8] = corr[j];
    }
    // final max + sum + write
    float m2 = -1e30f;
    #pragma unroll
    for (int i = 0; i < 8; ++i) m2 = fmaxf(m2, v[i]);
    #pragma unroll
    for (int o = 32; o > 0; o >>= 1) m2 = fmaxf(m2, __shfl_xor(m2, o, 64));
    if (lane == 0) redA[wid] = m2;
    __syncthreads();
    const float M2 = fmaxf(fmaxf(redA[0], redA[1]), fmaxf(redA[2], redA[3]));
    float l = 0.f;
    #pragma unroll
    for (int i = 0; i < 8; ++i) if (!msk[i]) { v[i] = __expf(v[i] - M2); l += v[i]; }
    #pragma unroll
    for (int o = 32; o > 0; o >>= 1) l += __shfl_xor(l, o, 64);
    if (lane == 0) redB[wid] = l;
    __syncthreads();
    const float inv = 1.f / (redB[0] + redB[1] + redB[2] + redB[3]);
    #pragma unroll
    for (int i = 0; i < 8; ++i) {
        int s = i * 256 + tid;
        row[s] = msk[i] ? 0 : f2bf(v[i] * inv);
    }
}

// ============ K4: row softmax over t (masked), wT bf16 -> attnT bf16 ============
__global__ __launch_bounds__(256) void softmax2_k(
    const unsigned short* __restrict__ wT, unsigned short* __restrict__ attnT,
    const int* __restrict__ src, int b0, size_t sW, size_t sAt)
{
    const int e = blockIdx.x, g = blockIdx.y, b = b0 + g, tid = threadIdx.x;
    const int lane = tid & 63, wid = tid >> 6;
    const unsigned short* row = wT + g * sW + (size_t)e * TT;
    unsigned short* orow = attnT + g * sAt + (size_t)e * TT;
    const int* sb = src + (size_t)b * SS;
    __shared__ float shm[4], shl[4];
    float v[8]; int msk[8];
    float m = -1e30f;
    #pragma unroll
    for (int i = 0; i < 8; ++i) {
        int tt = i * 256 + tid;
        msk[i] = (sb[tt] == 0);
        v[i] = msk[i] ? -1e30f : bf2f(row[tt]);
        m = fmaxf(m, v[i]);
    }
    #pragma unroll
    for (int o = 32; o > 0; o >>= 1) m = fmaxf(m, __shfl_xor(m, o, 64));
    if (lane == 0) shm[wid] = m;
    __syncthreads();
    const float M = fmaxf(fmaxf(shm[0], shm[1]), fmaxf(shm[2], shm[3]));
    float l = 0.f;
    #pragma unroll
    for (int i = 0; i < 8; ++i) if (!msk[i]) { v[i] = __expf(v[i] - M); l += v[i]; }
    #pragma unroll
    for (int o = 32; o > 0; o >>= 1) l += __shfl_xor(l, o, 64);
    if (lane == 0) shl[wid] = l;
    __syncthreads();
    const float inv = 1.f / (shl[0] + shl[1] + shl[2] + shl[3]);
    #pragma unroll
    for (int i = 0; i < 8; ++i) {
        int tt = i * 256 + tid;
        orow[tt] = msk[i] ? 0 : f2bf(v[i] * inv);
    }
}

extern "C" void kernel_launch(void* const* d_in, const int* in_sizes, int n_in,
                              void* d_out, int out_size, void* d_ws, size_t ws_size,
                              hipStream_t stream)
{
    const float* state = (const float*)d_in[0];
    const float* x     = (const float*)d_in[1];
    const int* src     = (const int*)d_in[2];
    float* out         = (float*)d_out;

    const size_t SD = (size_t)SS * DD;   // f32 elems per batch
    const size_t perP  = (size_t)SS * TT * 2;
    const size_t perST = (size_t)DD * SS * 2;
    const size_t perW  = (size_t)DD * TT * 2;
    const size_t perXB = (size_t)SS * DD * 2;
    const size_t perSB = (size_t)SS * DD * 2;
    const size_t perBatch = perP + perST + perW + perXB + perSB;

    int G = 8;
    while (G > 1 && (size_t)G * perBatch > ws_size) G >>= 1;

    char* base = (char*)d_ws;
    unsigned short* P  = (unsigned short*)base;
    unsigned short* ST = (unsigned short*)(base + (size_t)G * perP);
    unsigned short* W  = (unsigned short*)(base + (size_t)G * (perP + perST));
    unsigned short* XB = (unsigned short*)(base + (size_t)G * (perP + perST + perW));
    unsigned short* SB = (unsigned short*)(base + (size_t)G * (perP + perST + perW + perXB));

    const size_t sP  = (size_t)SS * TT;   // elems per g
    const size_t sST = (size_t)DD * SS;
    const size_t sW  = (size_t)DD * TT;
    const size_t sXB = (size_t)SS * DD;

    for (int b0 = 0; b0 < NB; b0 += G) {
        // prep: xbf bf16; stateT + statebf bf16
        conv_k<<<2048, 256, 0, stream>>>(x + (size_t)b0 * SD, XB, (size_t)G * SD);
        transpose_k<<<dim3(SS / 64, DD / 64, G), 256, 0, stream>>>(
            state + (size_t)b0 * SD, ST, SB, SD, sST, sXB);

        // K1: scoresT[t][s] = xbf . statebf^T   (bf16 out into P)
        gemm_nt<0><<<dim3(SS / 128, TT / 128, G), 256, 0, stream>>>(
            XB, SB, P, DD, DD, SS, DD, sXB, sXB, sP);

        // K2: softmax over s per row t, with fp32 window refinement; pT in place
        softmax1_k<<<dim3(TT, G), 256, 0, stream>>>(P, x, state, src, b0, sP);

        // K3: wT[d][t] = stateT . pT^T   (bf16 out)
        gemm_nt<0><<<dim3(TT / 128, DD / 128, G), 256, 0, stream>>>(
            ST, P, W, SS, SS, TT, SS, sST, sP, sW);

        // K4: softmax over t per row e; attnT bf16 into P (pT dead)
        softmax2_k<<<dim3(DD, G), 256, 0, stream>>>(W, P, src, b0, sW, sP);

        // K5: out[e][d] = attnT . stateT^T   (fp32 out, direct)
        gemm_nt<1><<<dim3(DD / 128, DD / 128, G), 256, 0, stream>>>(
            P, ST, out + (size_t)b0 * DD * DD, TT, SS, DD, TT, sP, sST, (size_t)DD * DD);
    }
}

// Round 6
// 353.422 us; speedup vs baseline: 7.9214x; 1.1623x over previous
//
#include <hip/hip_runtime.h>
#include <hip/hip_bf16.h>

#define SS 2048
#define TT 2048
#define DD 1024
#define NB 8

typedef __attribute__((ext_vector_type(8))) short short8v;     // MFMA bf16 operand
typedef __attribute__((ext_vector_type(8))) unsigned short us8;
typedef __attribute__((ext_vector_type(4))) unsigned short us4;
typedef __attribute__((ext_vector_type(4))) float f32x4;

__device__ __forceinline__ float bf2f(unsigned short u) {
    union { unsigned int i; float f; } v; v.i = ((unsigned int)u) << 16; return v.f;
}
__device__ __forceinline__ unsigned short f2bf(float f) {
    union { float f; unsigned int i; } v; v.f = f;
    unsigned int x = v.i;
    return (unsigned short)((x + 0x7fffu + ((x >> 16) & 1u)) >> 16);
}

// ============ xbf = bf16(x), elementwise ============
__global__ __launch_bounds__(256) void conv_k(
    const float* __restrict__ in, unsigned short* __restrict__ outv, size_t n)
{
    size_t i = ((size_t)blockIdx.x * 256 + threadIdx.x) * 8;
    const size_t stride = (size_t)gridDim.x * 256 * 8;
    for (; i < n; i += stride) {
        float4 a = *reinterpret_cast<const float4*>(in + i);
        float4 b = *reinterpret_cast<const float4*>(in + i + 4);
        us8 o;
        o[0] = f2bf(a.x); o[1] = f2bf(a.y); o[2] = f2bf(a.z); o[3] = f2bf(a.w);
        o[4] = f2bf(b.x); o[5] = f2bf(b.y); o[6] = f2bf(b.z); o[7] = f2bf(b.w);
        *reinterpret_cast<us8*>(outv + i) = o;
    }
}

// ============ stateT[d][s] bf16 + statebf[s][d] bf16 from state f32 ============
__global__ __launch_bounds__(256) void transpose_k(
    const float* __restrict__ in, unsigned short* __restrict__ outT,
    unsigned short* __restrict__ outB, size_t sIn, size_t sOutT, size_t sOutB)
{
    __shared__ float t[64][65];
    const int g = blockIdx.z;
    const float* I = in + g * sIn;            // [SS][DD]
    unsigned short* OT = outT + g * sOutT;    // [DD][SS]
    unsigned short* OB = outB + g * sOutB;    // [SS][DD]
    const int s0 = blockIdx.x * 64, d0 = blockIdx.y * 64;
    const int tid = threadIdx.x;
    #pragma unroll
    for (int i = 0; i < 4; ++i) {
        int slot = tid + i * 256;
        int rr = slot >> 4, rc = (slot & 15) * 4;
        float4 v = *reinterpret_cast<const float4*>(I + (size_t)(s0 + rr) * DD + d0 + rc);
        t[rr][rc + 0] = v.x; t[rr][rc + 1] = v.y; t[rr][rc + 2] = v.z; t[rr][rc + 3] = v.w;
        us4 o; o[0] = f2bf(v.x); o[1] = f2bf(v.y); o[2] = f2bf(v.z); o[3] = f2bf(v.w);
        *reinterpret_cast<us4*>(OB + (size_t)(s0 + rr) * DD + d0 + rc) = o;
    }
    __syncthreads();
    #pragma unroll
    for (int i = 0; i < 4; ++i) {
        int slot = tid + i * 256;
        int dr = slot >> 4, sidx = (slot & 15) * 4;
        us4 o;
        #pragma unroll
        for (int j = 0; j < 4; ++j) o[j] = f2bf(t[sidx + j][dr]);
        *reinterpret_cast<us4*>(OT + (size_t)(d0 + dr) * SS + s0 + sidx) = o;
    }
}

// ============ NT bf16 GEMM: dbuf LDS + prefetch + T2 swizzle, BK=64 ============
// (unchanged from R5)
template<int OUT_F32>
__global__ __launch_bounds__(256, 2) void gemm_nt(
    const unsigned short* __restrict__ A, const unsigned short* __restrict__ B,
    void* __restrict__ C, int lda, int ldb, int ldc, int K,
    size_t sA, size_t sB, size_t sC)
{
    __shared__ unsigned short As[2][128 * 64];
    __shared__ unsigned short Bs[2][128 * 64];
    const int g = blockIdx.z;
    const unsigned short* Ag = A + g * sA;
    const unsigned short* Bg = B + g * sB;
    const int m0 = blockIdx.y * 128, n0 = blockIdx.x * 128;
    const int tid = threadIdx.x, lane = tid & 63, wid = tid >> 6;
    const int wm = (wid >> 1) * 64, wn = (wid & 1) * 64;
    const int lr16 = lane & 15, lk = lane >> 4;
    const int sr = wid * 32 + (lane >> 3);
    const int sp = lane & 7;

    f32x4 acc[4][4] = {};
    const int NT = K >> 6;

#define STAGE(buf, kt)                                                          \
    {                                                                           \
        const int k0 = (kt) << 6;                                               \
        _Pragma("unroll")                                                       \
        for (int j = 0; j < 4; ++j) {                                           \
            int r = sr + j * 8;                                                 \
            int c = sp ^ (r & 7);                                               \
            __builtin_amdgcn_global_load_lds(                                   \
                (const __attribute__((address_space(1))) unsigned int*)        \
                    (Ag + (size_t)(m0 + r) * lda + k0 + c * 8),                 \
                (__attribute__((address_space(3))) unsigned int*)              \
                    (&As[buf][(wid * 32 + j * 8) * 64]),                        \
                16, 0, 0);                                                      \
            __builtin_amdgcn_global_load_lds(                                   \
                (const __attribute__((address_space(1))) unsigned int*)        \
                    (Bg + (size_t)(n0 + r) * ldb + k0 + c * 8),                 \
                (__attribute__((address_space(3))) unsigned int*)              \
                    (&Bs[buf][(wid * 32 + j * 8) * 64]),                        \
                16, 0, 0);                                                      \
        }                                                                       \
    }

    int cur = 0;
    STAGE(0, 0);
    __syncthreads();
    for (int kt = 0; kt < NT; ++kt) {
        if (kt + 1 < NT) STAGE(cur ^ 1, kt + 1);
        #pragma unroll
        for (int ks = 0; ks < 2; ++ks) {
            short8v a[4], bb[4];
            const int c = ks * 4 + lk;
            #pragma unroll
            for (int mi = 0; mi < 4; ++mi) {
                int r = wm + mi * 16 + lr16;
                a[mi] = *reinterpret_cast<const short8v*>(&As[cur][r * 64 + (c ^ (r & 7)) * 8]);
            }
            #pragma unroll
            for (int ni = 0; ni < 4; ++ni) {
                int r = wn + ni * 16 + lr16;
                bb[ni] = *reinterpret_cast<const short8v*>(&Bs[cur][r * 64 + (c ^ (r & 7)) * 8]);
            }
            #pragma unroll
            for (int ni = 0; ni < 4; ++ni)
                #pragma unroll
                for (int mi = 0; mi < 4; ++mi)
                    acc[mi][ni] = __builtin_amdgcn_mfma_f32_16x16x32_bf16(a[mi], bb[ni], acc[mi][ni], 0, 0, 0);
        }
        __syncthreads();
        cur ^= 1;
    }
#undef STAGE

    const int orow = (lane >> 4) * 4, ocol = lane & 15;
    if (OUT_F32) {
        float* Cg = (float*)C + g * sC;
        #pragma unroll
        for (int mi = 0; mi < 4; ++mi)
            #pragma unroll
            for (int ni = 0; ni < 4; ++ni)
                #pragma unroll
                for (int r = 0; r < 4; ++r)
                    Cg[(size_t)(m0 + wm + mi * 16 + orow + r) * ldc + (n0 + wn + ni * 16 + ocol)] = acc[mi][ni][r];
    } else {
        unsigned short* Cg = (unsigned short*)C + g * sC;
        #pragma unroll
        for (int mi = 0; mi < 4; ++mi)
            #pragma unroll
            for (int ni = 0; ni < 4; ++ni)
                #pragma unroll
                for (int r = 0; r < 4; ++r)
                    Cg[(size_t)(m0 + wm + mi * 16 + orow + r) * ldc + (n0 + wn + ni * 16 + ocol)] = f2bf(acc[mi][ni][r]);
    }
}

// ============ K2: row softmax over s + fp32 window refinement, bf16 in place =====
// Thread owns 8 CONTIGUOUS elems (vector loads). Refinement: one wave per
// flagged entry, full-1024 dot per wave, x row cached in registers.
__global__ __launch_bounds__(256) void softmax1_k(
    unsigned short* __restrict__ P, const float* __restrict__ x,
    const float* __restrict__ state, const int* __restrict__ src,
    int b0, size_t sP)
{
    const int t = blockIdx.x, g = blockIdx.y, b = b0 + g, tid = threadIdx.x;
    const int lane = tid & 63, wid = tid >> 6;
    unsigned short* row = P + g * sP + (size_t)t * SS;
    const int* sb = src + (size_t)b * SS;
    __shared__ float redA[4], redB[4];
    __shared__ int cnt, list[96];
    __shared__ float corr[96];

    us8 rv = *reinterpret_cast<const us8*>(row + tid * 8);
    int4 mk0 = reinterpret_cast<const int4*>(sb)[tid * 2];
    int4 mk1 = reinterpret_cast<const int4*>(sb)[tid * 2 + 1];
    int msk[8] = { mk0.x == 0, mk0.y == 0, mk0.z == 0, mk0.w == 0,
                   mk1.x == 0, mk1.y == 0, mk1.z == 0, mk1.w == 0 };
    float v[8];
    float m = -1e30f;
    #pragma unroll
    for (int i = 0; i < 8; ++i) {
        v[i] = msk[i] ? -1e30f : bf2f(rv[i]);
        m = fmaxf(m, v[i]);
    }
    #pragma unroll
    for (int o = 32; o > 0; o >>= 1) m = fmaxf(m, __shfl_xor(m, o, 64));
    if (lane == 0) redA[wid] = m;
    if (tid == 0) cnt = 0;
    __syncthreads();
    const float M = fmaxf(fmaxf(redA[0], redA[1]), fmaxf(redA[2], redA[3]));
    // flag entries within 16 of max (bf16 dot + storage error << 16)
    #pragma unroll
    for (int i = 0; i < 8; ++i) {
        if (!msk[i] && v[i] > M - 16.f) {
            int j = atomicAdd(&cnt, 1);
            if (j < 96) list[j] = tid * 8 + i;
        }
    }
    __syncthreads();
    const int n = min(cnt, 96);
    // x row cached: lane owns floats [lane*4 + c*256, +4), c=0..3
    const float* xr = x + (size_t)b * SS * DD + (size_t)t * DD;
    float4 xa[4];
    #pragma unroll
    for (int c = 0; c < 4; ++c) xa[c] = reinterpret_cast<const float4*>(xr)[lane + c * 64];
    for (int j = wid; j < n; j += 4) {
        const float* sr = state + (size_t)b * SS * DD + (size_t)list[j] * DD;
        float p = 0.f;
        #pragma unroll
        for (int c = 0; c < 4; ++c) {
            float4 c4 = reinterpret_cast<const float4*>(sr)[lane + c * 64];
            p += xa[c].x * c4.x + xa[c].y * c4.y + xa[c].z * c4.z + xa[c].w * c4.w;
        }
        #pragma unroll
        for (int o = 32; o > 0; o >>= 1) p += __shfl_xor(p, o, 64);
        if (lane == 0) corr[j] = p;
    }
    __syncthreads();
    for (int j = 0; j < n; ++j) {
        int s = list[j];
        if ((s >> 3) == tid) v[s & 7] = corr[j];
    }
    float m2 = -1e30f;
    #pragma unroll
    for (int i = 0; i < 8; ++i) m2 = fmaxf(m2, v[i]);
    #pragma unroll
    for (int o = 32; o > 0; o >>= 1) m2 = fmaxf(m2, __shfl_xor(m2, o, 64));
    if (lane == 0) redA[wid] = m2;
    __syncthreads();
    const float M2 = fmaxf(fmaxf(redA[0], redA[1]), fmaxf(redA[2], redA[3]));
    float l = 0.f;
    #pragma unroll
    for (int i = 0; i < 8; ++i) if (!msk[i]) { v[i] = __expf(v[i] - M2); l += v[i]; }
    #pragma unroll
    for (int o = 32; o > 0; o >>= 1) l += __shfl_xor(l, o, 64);
    if (lane == 0) redB[wid] = l;
    __syncthreads();
    const float inv = 1.f / (redB[0] + redB[1] + redB[2] + redB[3]);
    us8 ov;
    #pragma unroll
    for (int i = 0; i < 8; ++i) ov[i] = msk[i] ? 0 : f2bf(v[i] * inv);
    *reinterpret_cast<us8*>(row + tid * 8) = ov;
}

// ============ K4: row softmax over t (masked), wT bf16 -> attnT bf16, vectorized =
__global__ __launch_bounds__(256) void softmax2_k(
    const unsigned short* __restrict__ wT, unsigned short* __restrict__ attnT,
    const int* __restrict__ src, int b0, size_t sW, size_t sAt)
{
    const int e = blockIdx.x, g = blockIdx.y, b = b0 + g, tid = threadIdx.x;
    const int lane = tid & 63, wid = tid >> 6;
    const unsigned short* row = wT + g * sW + (size_t)e * TT;
    unsigned short* orow = attnT + g * sAt + (size_t)e * TT;
    const int* sb = src + (size_t)b * SS;
    __shared__ float shm[4], shl[4];
    us8 rv = *reinterpret_cast<const us8*>(row + tid * 8);
    int4 mk0 = reinterpret_cast<const int4*>(sb)[tid * 2];
    int4 mk1 = reinterpret_cast<const int4*>(sb)[tid * 2 + 1];
    int msk[8] = { mk0.x == 0, mk0.y == 0, mk0.z == 0, mk0.w == 0,
                   mk1.x == 0, mk1.y == 0, mk1.z == 0, mk1.w == 0 };
    float v[8];
    float m = -1e30f;
    #pragma unroll
    for (int i = 0; i < 8; ++i) {
        v[i] = msk[i] ? -1e30f : bf2f(rv[i]);
        m = fmaxf(m, v[i]);
    }
    #pragma unroll
    for (int o = 32; o > 0; o >>= 1) m = fmaxf(m, __shfl_xor(m, o, 64));
    if (lane == 0) shm[wid] = m;
    __syncthreads();
    const float M = fmaxf(fmaxf(shm[0], shm[1]), fmaxf(shm[2], shm[3]));
    float l = 0.f;
    #pragma unroll
    for (int i = 0; i < 8; ++i) if (!msk[i]) { v[i] = __expf(v[i] - M); l += v[i]; }
    #pragma unroll
    for (int o = 32; o > 0; o >>= 1) l += __shfl_xor(l, o, 64);
    if (lane == 0) shl[wid] = l;
    __syncthreads();
    const float inv = 1.f / (shl[0] + shl[1] + shl[2] + shl[3]);
    us8 ov;
    #pragma unroll
    for (int i = 0; i < 8; ++i) ov[i] = msk[i] ? 0 : f2bf(v[i] * inv);
    *reinterpret_cast<us8*>(orow + tid * 8) = ov;
}

extern "C" void kernel_launch(void* const* d_in, const int* in_sizes, int n_in,
                              void* d_out, int out_size, void* d_ws, size_t ws_size,
                              hipStream_t stream)
{
    const float* state = (const float*)d_in[0];
    const float* x     = (const float*)d_in[1];
    const int* src     = (const int*)d_in[2];
    float* out         = (float*)d_out;

    const size_t SD = (size_t)SS * DD;
    const size_t perP  = (size_t)SS * TT * 2;
    const size_t perST = (size_t)DD * SS * 2;
    const size_t perW  = (size_t)DD * TT * 2;
    const size_t perXB = (size_t)SS * DD * 2;
    const size_t perSB = (size_t)SS * DD * 2;
    const size_t perBatch = perP + perST + perW + perXB + perSB;

    int G = 8;
    while (G > 1 && (size_t)G * perBatch > ws_size) G >>= 1;

    char* base = (char*)d_ws;
    unsigned short* P  = (unsigned short*)base;
    unsigned short* ST = (unsigned short*)(base + (size_t)G * perP);
    unsigned short* W  = (unsigned short*)(base + (size_t)G * (perP + perST));
    unsigned short* XB = (unsigned short*)(base + (size_t)G * (perP + perST + perW));
    unsigned short* SB = (unsigned short*)(base + (size_t)G * (perP + perST + perW + perXB));

    const size_t sP  = (size_t)SS * TT;
    const size_t sST = (size_t)DD * SS;
    const size_t sW  = (size_t)DD * TT;
    const size_t sXB = (size_t)SS * DD;

    for (int b0 = 0; b0 < NB; b0 += G) {
        conv_k<<<2048, 256, 0, stream>>>(x + (size_t)b0 * SD, XB, (size_t)G * SD);
        transpose_k<<<dim3(SS / 64, DD / 64, G), 256, 0, stream>>>(
            state + (size_t)b0 * SD, ST, SB, SD, sST, sXB);

        // K1: scoresT[t][s] = xbf . statebf^T   (bf16 out into P)
        gemm_nt<0><<<dim3(SS / 128, TT / 128, G), 256, 0, stream>>>(
            XB, SB, P, DD, DD, SS, DD, sXB, sXB, sP);

        // K2: softmax over s per row t, with fp32 window refinement; pT in place
        softmax1_k<<<dim3(TT, G), 256, 0, stream>>>(P, x, state, src, b0, sP);

        // K3: wT[d][t] = stateT . pT^T   (bf16 out)
        gemm_nt<0><<<dim3(TT / 128, DD / 128, G), 256, 0, stream>>>(
            ST, P, W, SS, SS, TT, SS, sST, sP, sW);

        // K4: softmax over t per row e; attnT bf16 into P (pT dead)
        softmax2_k<<<dim3(DD, G), 256, 0, stream>>>(W, P, src, b0, sW, sP);

        // K5: out[e][d] = attnT . stateT^T   (fp32 out, direct)
        gemm_nt<1><<<dim3(DD / 128, DD / 128, G), 256, 0, stream>>>(
            P, ST, out + (size_t)b0 * DD * DD, TT, SS, DD, TT, sP, sST, (size_t)DD * DD);
    }
}

// Round 7
// 337.358 us; speedup vs baseline: 8.2986x; 1.0476x over previous
//
#include <hip/hip_runtime.h>
#include <hip/hip_bf16.h>

#define SS 2048
#define TT 2048
#define DD 1024
#define NB 8

typedef __attribute__((ext_vector_type(8))) short short8v;     // MFMA bf16 operand
typedef __attribute__((ext_vector_type(8))) unsigned short us8;
typedef __attribute__((ext_vector_type(4))) unsigned short us4;
typedef __attribute__((ext_vector_type(4))) float f32x4;

__device__ __forceinline__ float bf2f(unsigned short u) {
    union { unsigned int i; float f; } v; v.i = ((unsigned int)u) << 16; return v.f;
}
__device__ __forceinline__ unsigned short f2bf(float f) {
    union { float f; unsigned int i; } v; v.f = f;
    unsigned int x = v.i;
    return (unsigned short)((x + 0x7fffu + ((x >> 16) & 1u)) >> 16);
}

// ============ xbf = bf16(x), elementwise ============
__global__ __launch_bounds__(256) void conv_k(
    const float* __restrict__ in, unsigned short* __restrict__ outv, size_t n)
{
    size_t i = ((size_t)blockIdx.x * 256 + threadIdx.x) * 8;
    const size_t stride = (size_t)gridDim.x * 256 * 8;
    for (; i < n; i += stride) {
        float4 a = *reinterpret_cast<const float4*>(in + i);
        float4 b = *reinterpret_cast<const float4*>(in + i + 4);
        us8 o;
        o[0] = f2bf(a.x); o[1] = f2bf(a.y); o[2] = f2bf(a.z); o[3] = f2bf(a.w);
        o[4] = f2bf(b.x); o[5] = f2bf(b.y); o[6] = f2bf(b.z); o[7] = f2bf(b.w);
        *reinterpret_cast<us8*>(outv + i) = o;
    }
}

// ============ stateT[d][s] bf16 + statebf[s][d] bf16 from state f32 ============
__global__ __launch_bounds__(256) void transpose_k(
    const float* __restrict__ in, unsigned short* __restrict__ outT,
    unsigned short* __restrict__ outB, size_t sIn, size_t sOutT, size_t sOutB)
{
    __shared__ float t[64][65];
    const int g = blockIdx.z;
    const float* I = in + g * sIn;            // [SS][DD]
    unsigned short* OT = outT + g * sOutT;    // [DD][SS]
    unsigned short* OB = outB + g * sOutB;    // [SS][DD]
    const int s0 = blockIdx.x * 64, d0 = blockIdx.y * 64;
    const int tid = threadIdx.x;
    #pragma unroll
    for (int i = 0; i < 4; ++i) {
        int slot = tid + i * 256;
        int rr = slot >> 4, rc = (slot & 15) * 4;
        float4 v = *reinterpret_cast<const float4*>(I + (size_t)(s0 + rr) * DD + d0 + rc);
        t[rr][rc + 0] = v.x; t[rr][rc + 1] = v.y; t[rr][rc + 2] = v.z; t[rr][rc + 3] = v.w;
        us4 o; o[0] = f2bf(v.x); o[1] = f2bf(v.y); o[2] = f2bf(v.z); o[3] = f2bf(v.w);
        *reinterpret_cast<us4*>(OB + (size_t)(s0 + rr) * DD + d0 + rc) = o;
    }
    __syncthreads();
    #pragma unroll
    for (int i = 0; i < 4; ++i) {
        int slot = tid + i * 256;
        int dr = slot >> 4, sidx = (slot & 15) * 4;
        us4 o;
        #pragma unroll
        for (int j = 0; j < 4; ++j) o[j] = f2bf(t[sidx + j][dr]);
        *reinterpret_cast<us4*>(OT + (size_t)(d0 + dr) * SS + s0 + sidx) = o;
    }
}

// ============ NT bf16 GEMM: dbuf LDS + prefetch + swizzle, BK=32, 3 blk/CU ======
// C[m][n] = sum_k A[m,k]*B[n,k]. 128x128 tile, 4 waves, 4x4 frags/wave.
// LDS row = 64B (32 bf16); 16B chunk c of row r lives at slot c^((r>>1)&3).
// T1: bijective XCD-chunked blockIdx swizzle, cpx = nwg/8 (= one batch's grid).
template<int OUT_F32>
__global__ __launch_bounds__(256, 3) void gemm_nt(
    const unsigned short* __restrict__ A, const unsigned short* __restrict__ B,
    void* __restrict__ C, int lda, int ldb, int ldc, int K,
    size_t sA, size_t sB, size_t sC)
{
    __shared__ unsigned short As[2][128 * 32];
    __shared__ unsigned short Bs[2][128 * 32];

    // ---- T1 XCD swizzle (bijective; all grids here are multiples of 8) ----
    const int nxy = gridDim.x * gridDim.y;
    const int nwg = nxy * gridDim.z;
    int wg = blockIdx.x + gridDim.x * (blockIdx.y + gridDim.y * blockIdx.z);
    if ((nwg & 7) == 0) {
        const int cpx = nwg >> 3;
        wg = (wg & 7) * cpx + (wg >> 3);
    }
    const int g  = wg / nxy;
    const int rm = wg - g * nxy;
    const int by = rm / gridDim.x;
    const int bx = rm - by * gridDim.x;

    const unsigned short* Ag = A + g * sA;
    const unsigned short* Bg = B + g * sB;
    const int m0 = by * 128, n0 = bx * 128;
    const int tid = threadIdx.x, lane = tid & 63, wid = tid >> 6;
    const int wm = (wid >> 1) * 64, wn = (wid & 1) * 64;
    const int lr16 = lane & 15, lk = lane >> 4;           // frag row / k-chunk
    const int sr = wid * 32 + (lane >> 2);                // staging row (j*16 added)
    const int sp = lane & 3;                              // staging chunk slot

    f32x4 acc[4][4] = {};
    const int NT = K >> 5;

#define STAGE(buf, kt)                                                          \
    {                                                                           \
        const int k0 = (kt) << 5;                                               \
        _Pragma("unroll")                                                       \
        for (int j = 0; j < 2; ++j) {                                           \
            int r = sr + j * 16;                                                \
            int c = sp ^ ((r >> 1) & 3);                                        \
            __builtin_amdgcn_global_load_lds(                                   \
                (const __attribute__((address_space(1))) unsigned int*)        \
                    (Ag + (size_t)(m0 + r) * lda + k0 + c * 8),                 \
                (__attribute__((address_space(3))) unsigned int*)              \
                    (&As[buf][(wid * 32 + j * 16) * 32]),                       \
                16, 0, 0);                                                      \
            __builtin_amdgcn_global_load_lds(                                   \
                (const __attribute__((address_space(1))) unsigned int*)        \
                    (Bg + (size_t)(n0 + r) * ldb + k0 + c * 8),                 \
                (__attribute__((address_space(3))) unsigned int*)              \
                    (&Bs[buf][(wid * 32 + j * 16) * 32]),                       \
                16, 0, 0);                                                      \
        }                                                                       \
    }

    int cur = 0;
    STAGE(0, 0);
    __syncthreads();
    for (int kt = 0; kt < NT; ++kt) {
        if (kt + 1 < NT) STAGE(cur ^ 1, kt + 1);
        short8v a[4], bb[4];
        #pragma unroll
        for (int mi = 0; mi < 4; ++mi) {
            int r = wm + mi * 16 + lr16;
            a[mi] = *reinterpret_cast<const short8v*>(
                &As[cur][r * 32 + (lk ^ ((r >> 1) & 3)) * 8]);
        }
        #pragma unroll
        for (int ni = 0; ni < 4; ++ni) {
            int r = wn + ni * 16 + lr16;
            bb[ni] = *reinterpret_cast<const short8v*>(
                &Bs[cur][r * 32 + (lk ^ ((r >> 1) & 3)) * 8]);
        }
        #pragma unroll
        for (int ni = 0; ni < 4; ++ni)
            #pragma unroll
            for (int mi = 0; mi < 4; ++mi)
                acc[mi][ni] = __builtin_amdgcn_mfma_f32_16x16x32_bf16(a[mi], bb[ni], acc[mi][ni], 0, 0, 0);
        __syncthreads();
        cur ^= 1;
    }
#undef STAGE

    const int orow = (lane >> 4) * 4, ocol = lane & 15;
    if (OUT_F32) {
        float* Cg = (float*)C + g * sC;
        #pragma unroll
        for (int mi = 0; mi < 4; ++mi)
            #pragma unroll
            for (int ni = 0; ni < 4; ++ni)
                #pragma unroll
                for (int r = 0; r < 4; ++r)
                    Cg[(size_t)(m0 + wm + mi * 16 + orow + r) * ldc + (n0 + wn + ni * 16 + ocol)] = acc[mi][ni][r];
    } else {
        unsigned short* Cg = (unsigned short*)C + g * sC;
        #pragma unroll
        for (int mi = 0; mi < 4; ++mi)
            #pragma unroll
            for (int ni = 0; ni < 4; ++ni)
                #pragma unroll
                for (int r = 0; r < 4; ++r)
                    Cg[(size_t)(m0 + wm + mi * 16 + orow + r) * ldc + (n0 + wn + ni * 16 + ocol)] = f2bf(acc[mi][ni][r]);
    }
}

// ============ K2: row softmax over s + fp32 window refinement, bf16 in place =====
__global__ __launch_bounds__(256) void softmax1_k(
    unsigned short* __restrict__ P, const float* __restrict__ x,
    const float* __restrict__ state, const int* __restrict__ src,
    int b0, size_t sP)
{
    const int t = blockIdx.x, g = blockIdx.y, b = b0 + g, tid = threadIdx.x;
    const int lane = tid & 63, wid = tid >> 6;
    unsigned short* row = P + g * sP + (size_t)t * SS;
    const int* sb = src + (size_t)b * SS;
    __shared__ float redA[4], redB[4];
    __shared__ int cnt, list[96];
    __shared__ float corr[96];

    us8 rv = *reinterpret_cast<const us8*>(row + tid * 8);
    int4 mk0 = reinterpret_cast<const int4*>(sb)[tid * 2];
    int4 mk1 = reinterpret_cast<const int4*>(sb)[tid * 2 + 1];
    int msk[8] = { mk0.x == 0, mk0.y == 0, mk0.z == 0, mk0.w == 0,
                   mk1.x == 0, mk1.y == 0, mk1.z == 0, mk1.w == 0 };
    float v[8];
    float m = -1e30f;
    #pragma unroll
    for (int i = 0; i < 8; ++i) {
        v[i] = msk[i] ? -1e30f : bf2f(rv[i]);
        m = fmaxf(m, v[i]);
    }
    #pragma unroll
    for (int o = 32; o > 0; o >>= 1) m = fmaxf(m, __shfl_xor(m, o, 64));
    if (lane == 0) redA[wid] = m;
    if (tid == 0) cnt = 0;
    __syncthreads();
    const float M = fmaxf(fmaxf(redA[0], redA[1]), fmaxf(redA[2], redA[3]));
    #pragma unroll
    for (int i = 0; i < 8; ++i) {
        if (!msk[i] && v[i] > M - 16.f) {
            int j = atomicAdd(&cnt, 1);
            if (j < 96) list[j] = tid * 8 + i;
        }
    }
    __syncthreads();
    const int n = min(cnt, 96);
    const float* xr = x + (size_t)b * SS * DD + (size_t)t * DD;
    float4 xa[4];
    #pragma unroll
    for (int c = 0; c < 4; ++c) xa[c] = reinterpret_cast<const float4*>(xr)[lane + c * 64];
    for (int j = wid; j < n; j += 4) {
        const float* sr = state + (size_t)b * SS * DD + (size_t)list[j] * DD;
        float p = 0.f;
        #pragma unroll
        for (int c = 0; c < 4; ++c) {
            float4 c4 = reinterpret_cast<const float4*>(sr)[lane + c * 64];
            p += xa[c].x * c4.x + xa[c].y * c4.y + xa[c].z * c4.z + xa[c].w * c4.w;
        }
        #pragma unroll
        for (int o = 32; o > 0; o >>= 1) p += __shfl_xor(p, o, 64);
        if (lane == 0) corr[j] = p;
    }
    __syncthreads();
    for (int j = 0; j < n; ++j) {
        int s = list[j];
        if ((s >> 3) == tid) v[s & 7] = corr[j];
    }
    float m2 = -1e30f;
    #pragma unroll
    for (int i = 0; i < 8; ++i) m2 = fmaxf(m2, v[i]);
    #pragma unroll
    for (int o = 32; o > 0; o >>= 1) m2 = fmaxf(m2, __shfl_xor(m2, o, 64));
    if (lane == 0) redA[wid] = m2;
    __syncthreads();
    const float M2 = fmaxf(fmaxf(redA[0], redA[1]), fmaxf(redA[2], redA[3]));
    float l = 0.f;
    #pragma unroll
    for (int i = 0; i < 8; ++i) if (!msk[i]) { v[i] = __expf(v[i] - M2); l += v[i]; }
    #pragma unroll
    for (int o = 32; o > 0; o >>= 1) l += __shfl_xor(l, o, 64);
    if (lane == 0) redB[wid] = l;
    __syncthreads();
    const float inv = 1.f / (redB[0] + redB[1] + redB[2] + redB[3]);
    us8 ov;
    #pragma unroll
    for (int i = 0; i < 8; ++i) ov[i] = msk[i] ? 0 : f2bf(v[i] * inv);
    *reinterpret_cast<us8*>(row + tid * 8) = ov;
}

// ============ K4: row softmax over t (masked), wT bf16 -> attnT bf16, vectorized =
__global__ __launch_bounds__(256) void softmax2_k(
    const unsigned short* __restrict__ wT, unsigned short* __restrict__ attnT,
    const int* __restrict__ src, int b0, size_t sW, size_t sAt)
{
    const int e = blockIdx.x, g = blockIdx.y, b = b0 + g, tid = threadIdx.x;
    const int lane = tid & 63, wid = tid >> 6;
    const unsigned short* row = wT + g * sW + (size_t)e * TT;
    unsigned short* orow = attnT + g * sAt + (size_t)e * TT;
    const int* sb = src + (size_t)b * SS;
    __shared__ float shm[4], shl[4];
    us8 rv = *reinterpret_cast<const us8*>(row + tid * 8);
    int4 mk0 = reinterpret_cast<const int4*>(sb)[tid * 2];
    int4 mk1 = reinterpret_cast<const int4*>(sb)[tid * 2 + 1];
    int msk[8] = { mk0.x == 0, mk0.y == 0, mk0.z == 0, mk0.w == 0,
                   mk1.x == 0, mk1.y == 0, mk1.z == 0, mk1.w == 0 };
    float v[8];
    float m = -1e30f;
    #pragma unroll
    for (int i = 0; i < 8; ++i) {
        v[i] = msk[i] ? -1e30f : bf2f(rv[i]);
        m = fmaxf(m, v[i]);
    }
    #pragma unroll
    for (int o = 32; o > 0; o >>= 1) m = fmaxf(m, __shfl_xor(m, o, 64));
    if (lane == 0) shm[wid] = m;
    __syncthreads();
    const float M = fmaxf(fmaxf(shm[0], shm[1]), fmaxf(shm[2], shm[3]));
    float l = 0.f;
    #pragma unroll
    for (int i = 0; i < 8; ++i) if (!msk[i]) { v[i] = __expf(v[i] - M); l += v[i]; }
    #pragma unroll
    for (int o = 32; o > 0; o >>= 1) l += __shfl_xor(l, o, 64);
    if (lane == 0) shl[wid] = l;
    __syncthreads();
    const float inv = 1.f / (shl[0] + shl[1] + shl[2] + shl[3]);
    us8 ov;
    #pragma unroll
    for (int i = 0; i < 8; ++i) ov[i] = msk[i] ? 0 : f2bf(v[i] * inv);
    *reinterpret_cast<us8*>(orow + tid * 8) = ov;
}

extern "C" void kernel_launch(void* const* d_in, const int* in_sizes, int n_in,
                              void* d_out, int out_size, void* d_ws, size_t ws_size,
                              hipStream_t stream)
{
    const float* state = (const float*)d_in[0];
    const float* x     = (const float*)d_in[1];
    const int* src     = (const int*)d_in[2];
    float* out         = (float*)d_out;

    const size_t SD = (size_t)SS * DD;
    const size_t perP  = (size_t)SS * TT * 2;
    const size_t perST = (size_t)DD * SS * 2;
    const size_t perW  = (size_t)DD * TT * 2;
    const size_t perXB = (size_t)SS * DD * 2;
    const size_t perSB = (size_t)SS * DD * 2;
    const size_t perBatch = perP + perST + perW + perXB + perSB;

    int G = 8;
    while (G > 1 && (size_t)G * perBatch > ws_size) G >>= 1;

    char* base = (char*)d_ws;
    unsigned short* P  = (unsigned short*)base;
    unsigned short* ST = (unsigned short*)(base + (size_t)G * perP);
    unsigned short* W  = (unsigned short*)(base + (size_t)G * (perP + perST));
    unsigned short* XB = (unsigned short*)(base + (size_t)G * (perP + perST + perW));
    unsigned short* SB = (unsigned short*)(base + (size_t)G * (perP + perST + perW + perXB));

    const size_t sP  = (size_t)SS * TT;
    const size_t sST = (size_t)DD * SS;
    const size_t sW  = (size_t)DD * TT;
    const size_t sXB = (size_t)SS * DD;

    for (int b0 = 0; b0 < NB; b0 += G) {
        conv_k<<<2048, 256, 0, stream>>>(x + (size_t)b0 * SD, XB, (size_t)G * SD);
        transpose_k<<<dim3(SS / 64, DD / 64, G), 256, 0, stream>>>(
            state + (size_t)b0 * SD, ST, SB, SD, sST, sXB);

        // K1: scoresT[t][s] = xbf . statebf^T   (bf16 out into P)
        gemm_nt<0><<<dim3(SS / 128, TT / 128, G), 256, 0, stream>>>(
            XB, SB, P, DD, DD, SS, DD, sXB, sXB, sP);

        // K2: softmax over s per row t, with fp32 window refinement; pT in place
        softmax1_k<<<dim3(TT, G), 256, 0, stream>>>(P, x, state, src, b0, sP);

        // K3: wT[d][t] = stateT . pT^T   (bf16 out)
        gemm_nt<0><<<dim3(TT / 128, DD / 128, G), 256, 0, stream>>>(
            ST, P, W, SS, SS, TT, SS, sST, sP, sW);

        // K4: softmax over t per row e; attnT bf16 into P (pT dead)
        softmax2_k<<<dim3(DD, G), 256, 0, stream>>>(W, P, src, b0, sW, sP);

        // K5: out[e][d] = attnT . stateT^T   (fp32 out, direct)
        gemm_nt<1><<<dim3(DD / 128, DD / 128, G), 256, 0, stream>>>(
            P, ST, out + (size_t)b0 * DD * DD, TT, SS, DD, TT, sP, sST, (size_t)DD * DD);
    }
}